// Round 2
// baseline (230.773 us; speedup 1.0000x reference)
//
#include <hip/hip_runtime.h>

// BlockSample R8: no-LDS register-window version.
//
// History: R6 (comb 1KB-stride-12KB stores, 24 w/CU, LDS) ~= R7 (fully linear
// stores, 12 w/CU, LDS) ~= 90us kernel -> store ADDRESS pattern is not the
// limiter. Harness poison fill proves 6.7 TB/s writes at 3 waves/CU with a
// dependency-free store stream. Shared limiter in R6/R7: every 16B store
// depended on 4 ds_read_b32 + __syncthreads fences chopping the pipeline.
//
// R8: thread t = (ch = t>>2, i = t&3) holds its input row segment
// (rows y+i-3, cols [x0-4, x0+28), 8 float4 = 32 VGPR) in REGISTERS; each
// pixel's output float4 is a 4-float sliding window = v_movs only. No LDS,
// no barriers. 3 tasks (y0, y0+16, y0+32) fully unrolled with next-task
// loads issued before current-task stores (T14): steady-state store stream
// is dependency-free like the fill. Store layout as R7: lane slot = ch*4+i,
// 12KB/pixel written linearly by 12 waves. b == id&7 -> per-XCD input slice
// 1.77MB L2-resident (loads are 4-lane gathers, ~8us, hidden under stores).
// Prediction: kernel ~90 -> ~45us, dur_us -> 175-205.

#define CC 192
#define HH 48
#define WW 48
#define PXB 24              // pixels per task (x-chunk)
#define TPB 768             // 12 waves; thread t <-> (ch = t>>2, i = t&3)
#define NBLK 256            // 1 block/CU; 3 tasks each; 8*16*2*3 = 768 tasks

typedef float vfloat4 __attribute__((ext_vector_type(4)));

// window float k (0..31) of task r
#define W(r, k) (s[r][(k) >> 2][(k) & 3])

__global__ __launch_bounds__(TPB) void
blocksample_kernel(const float* __restrict__ in, float* __restrict__ out) {
    const int t  = threadIdx.x;
    const int id = blockIdx.x;
    const int b  = id & 7;         // XCD-partitioned batch
    const int k  = id >> 3;        // 0..31
    const int xh = k & 1;          // x-chunk
    const int y0 = k >> 1;         // tasks: y0, y0+16, y0+32
    const int x0 = PXB * xh;

    const int i      = t & 3;
    const int ch     = t >> 2;
    const bool masked = (i == 3);  // taps (3,2),(3,3) -> v.z,v.w zeroed

    const float* rowbase = in + ((size_t)(b * CC + ch) * HH) * WW;

    vfloat4 s[3][8];
    #pragma unroll
    for (int r = 0; r < 3; ++r)
        #pragma unroll
        for (int q = 0; q < 8; ++q) s[r][q] = (vfloat4)(0.0f);

    // Load row y+i-3, global cols [x0-4, x0+28) into s[r]. Col q=0 (xh==0)
    // and q=7 (xh==1) stay zero: they are the x-edge zero padding.
#define LOADW(r, yy) do {                                                     \
        const int row = (yy) + i - 3;                                         \
        if (row >= 0 && row < HH) {                                           \
            const float* p = rowbase + (size_t)row * WW + (x0 - 4);           \
            _Pragma("unroll")                                                 \
            for (int q = 0; q < 8; ++q) {                                     \
                const int colg = x0 - 4 + 4 * q;                              \
                if (colg >= 0 && colg <= WW - 4)                              \
                    s[r][q] = *(const vfloat4*)(p + 4 * q);                   \
            }                                                                 \
        }                                                                     \
    } while (0)

    // Store task r: pixel x = x0+px; thread t writes float4 slot t (=ch*4+i)
    // of the pixel's 12KB block; v[j] = window[px+2+j] = in col x+j-2.
#define STOREW(r, yy) do {                                                    \
        vfloat4* op = (vfloat4*)out                                           \
            + ((size_t)((b * HH + (yy)) * WW + x0)) * (CC * 4) + t;           \
        _Pragma("unroll")                                                     \
        for (int px = 0; px < PXB; ++px) {                                    \
            vfloat4 v;                                                        \
            v.x = W(r, px + 2);                                               \
            v.y = W(r, px + 3);                                               \
            v.z = masked ? 0.0f : W(r, px + 4);                               \
            v.w = masked ? 0.0f : W(r, px + 5);                               \
            op[(size_t)px * (CC * 4)] = v;                                    \
        }                                                                     \
    } while (0)

    LOADW(0, y0);           // task 0 loads in flight
    LOADW(1, y0 + 16);      // task 1 loads in flight (T14)
    STOREW(0, y0);
    LOADW(2, y0 + 32);      // issue before consuming s[1]
    STOREW(1, y0 + 16);
    STOREW(2, y0 + 32);

#undef LOADW
#undef STOREW
}

extern "C" void kernel_launch(void* const* d_in, const int* in_sizes, int n_in,
                              void* d_out, int out_size, void* d_ws, size_t ws_size,
                              hipStream_t stream) {
    const float* in = (const float*)d_in[0];
    float* out = (float*)d_out;
    blocksample_kernel<<<dim3(NBLK), dim3(TPB), 0, stream>>>(in, out);
}